// Round 3
// baseline (229.338 us; speedup 1.0000x reference)
//
#include <hip/hip_runtime.h>
#include <hip/hip_bf16.h>
#include <math.h>

#define S_LEN 2048
#define D_KV  64
#define BQ    128   // q rows per block = 4 waves x 32
#define BK    64
#define LP    72    // LDS row stride (bf16 elems): %8==0 for aligned b128
#define NW    4

typedef __attribute__((ext_vector_type(8)))  short bh8;    // 8 bf16 (A/B frag)
typedef __attribute__((ext_vector_type(4)))  short sh4;
typedef __attribute__((ext_vector_type(16))) float f32x16; // 32x32 C/D frag

__device__ __forceinline__ short f2bf(float f) {
    unsigned u = __builtin_bit_cast(unsigned, f);
    u += 0x7fffu + ((u >> 16) & 1u);   // RNE
    return (short)(u >> 16);
}

__global__ __launch_bounds__(256, 2)
void attn_fwd(const float* __restrict__ Qg, const float* __restrict__ Kg,
              const float* __restrict__ Vg, const float* __restrict__ Mg,
              float* __restrict__ Og)
{
    __shared__ __align__(16) short k_lds[BK * LP];      // K[k][d] bf16
    __shared__ __align__(16) short v_lds[D_KV * LP];    // V^T[d][k] bf16
    __shared__ __align__(16) short p_lds[NW * 32 * LP]; // per-wave P[q][k] bf16

    const int tid  = threadIdx.x;
    const int wave = tid >> 6;
    const int lane = tid & 63;
    const int n    = lane & 31;   // col within 32
    const int hi   = lane >> 5;   // half-wave 0/1

    const int qt = blockIdx.x;    // q tile (0..15)
    const int bh = blockIdx.y;    // 0..31
    const int b  = bh >> 4;       // / H

    const int qw = qt * BQ + wave * 32;   // wave's base q row

    const float* Qp = Qg + ((size_t)bh * S_LEN + qw) * D_KV;
    const float* Kp = Kg + (size_t)bh * S_LEN * D_KV;
    const float* Vp = Vg + (size_t)bh * S_LEN * D_KV;
    const float* Mp = Mg + (size_t)b * S_LEN * S_LEN;
    float*       Op = Og + ((size_t)bh * S_LEN + qw) * D_KV;

    // ---- Q A-frags: A[m = n][k = kc*16 + hi*8 + j], scale 1/8 folded (pow2) ----
    bh8 qf[4];
#pragma unroll
    for (int kc = 0; kc < 4; ++kc) {
        const float* src = Qp + n * D_KV + kc * 16 + hi * 8;
        float4 a0 = *(const float4*)(src);
        float4 a1 = *(const float4*)(src + 4);
        bh8 f;
        f[0] = f2bf(a0.x * 0.125f); f[1] = f2bf(a0.y * 0.125f);
        f[2] = f2bf(a0.z * 0.125f); f[3] = f2bf(a0.w * 0.125f);
        f[4] = f2bf(a1.x * 0.125f); f[5] = f2bf(a1.y * 0.125f);
        f[6] = f2bf(a1.z * 0.125f); f[7] = f2bf(a1.w * 0.125f);
        qf[kc] = f;
    }

    f32x16 o0, o1;          // O accumulators, d-cols [0,32) and [32,64)
    float  l_r[16];         // per-lane partial row sums (rows = f(reg,hi))
#pragma unroll
    for (int i = 0; i < 16; ++i) { o0[i] = 0.f; o1[i] = 0.f; l_r[i] = 0.f; }

    for (int kt = 0; kt < S_LEN; kt += BK) {
        // ---- stage K tile: 64x64 fp32 -> bf16 ----
#pragma unroll
        for (int i = 0; i < 4; ++i) {
            int idx = tid + 256 * i;
            int kr  = idx >> 4;
            int db  = (idx & 15) * 4;
            float4 kv = *(const float4*)(Kp + (size_t)(kt + kr) * D_KV + db);
            sh4 s4;
            s4[0] = f2bf(kv.x); s4[1] = f2bf(kv.y);
            s4[2] = f2bf(kv.z); s4[3] = f2bf(kv.w);
            *(sh4*)&k_lds[kr * LP + db] = s4;
        }
        // ---- stage V transposed: wave w covers d-cols [w*16, w*16+16) ----
        {
            int kr = lane;
#pragma unroll
            for (int i = 0; i < 4; ++i) {
                int db = wave * 16 + i * 4;
                float4 vv = *(const float4*)(Vp + (size_t)(kt + kr) * D_KV + db);
                v_lds[(db + 0) * LP + kr] = f2bf(vv.x);
                v_lds[(db + 1) * LP + kr] = f2bf(vv.y);
                v_lds[(db + 2) * LP + kr] = f2bf(vv.z);
                v_lds[(db + 3) * LP + kr] = f2bf(vv.w);
            }
        }
        __syncthreads();

        // ---- QK^T: two 32x32 score tiles over K=64 ----
        f32x16 s0, s1;
#pragma unroll
        for (int i = 0; i < 16; ++i) { s0[i] = 0.f; s1[i] = 0.f; }
#pragma unroll
        for (int kc = 0; kc < 4; ++kc) {
            int off = kc * 16 + hi * 8;
            bh8 b0 = *(const bh8*)&k_lds[n * LP + off];           // keys 0..31
            bh8 b1 = *(const bh8*)&k_lds[(32 + n) * LP + off];    // keys 32..63
            s0 = __builtin_amdgcn_mfma_f32_32x32x16_bf16(qf[kc], b0, s0, 0, 0, 0);
            s1 = __builtin_amdgcn_mfma_f32_32x32x16_bf16(qf[kc], b1, s1, 0, 0, 0);
        }

        // ---- mask + keep-positive + exp with FIXED max 0 ----
        // C/D: row = (r&3) + 8*(r>>2) + 4*hi, col = n.
        short* pw = &p_lds[wave * 32 * LP];
        const float* mb = Mp + (size_t)(qw + 4 * hi) * S_LEN + kt + n;
#pragma unroll
        for (int r = 0; r < 16; ++r) {
            int rowo = (r & 3) + 8 * (r >> 2);
            const float* mrow = mb + (size_t)rowo * S_LEN;
            float m0 = mrow[0];
            float m1 = mrow[32];
            float t0 = s0[r] * m0;
            float t1 = s1[r] * m1;
            float p0 = (t0 > 0.f) ? __expf(t0) : 0.f;
            float p1 = (t1 > 0.f) ? __expf(t1) : 0.f;
            l_r[r] += p0 + p1;
            int prow = (rowo + 4 * hi) * LP;
            pw[prow + n]      = f2bf(p0);
            pw[prow + 32 + n] = f2bf(p1);
        }

        // ---- PV: O[32 q][64 d] += P[32 q][64 k] * V[64 k][64 d] ----
        // same-wave RAW on pw: LDS ops are in-order; compiler inserts lgkmcnt
#pragma unroll
        for (int kc = 0; kc < 4; ++kc) {
            int off = kc * 16 + hi * 8;
            bh8 pa = *(const bh8*)&pw[n * LP + off];
            bh8 v0 = *(const bh8*)&v_lds[n * LP + off];           // d 0..31
            bh8 v1 = *(const bh8*)&v_lds[(32 + n) * LP + off];    // d 32..63
            o0 = __builtin_amdgcn_mfma_f32_32x32x16_bf16(pa, v0, o0, 0, 0, 0);
            o1 = __builtin_amdgcn_mfma_f32_32x32x16_bf16(pa, v1, o1, 0, 0, 0);
        }
        __syncthreads();   // protect k_lds/v_lds before next staging
    }

    // ---- one-time l reduction across the 32 lanes sharing each row ----
#pragma unroll
    for (int r = 0; r < 16; ++r) {
#pragma unroll
        for (int off = 16; off >= 1; off >>= 1)
            l_r[r] += __shfl_xor(l_r[r], off, 32);
    }

    // ---- epilogue: O / l ----
#pragma unroll
    for (int r = 0; r < 16; ++r) {
        int qrow = (r & 3) + 8 * (r >> 2) + 4 * hi;
        float inv = 1.0f / l_r[r];
        Op[(size_t)qrow * D_KV + n]      = o0[r] * inv;
        Op[(size_t)qrow * D_KV + 32 + n] = o1[r] * inv;
    }
}

extern "C" void kernel_launch(void* const* d_in, const int* in_sizes, int n_in,
                              void* d_out, int out_size, void* d_ws, size_t ws_size,
                              hipStream_t stream) {
    const float* Q = (const float*)d_in[0];
    const float* K = (const float*)d_in[1];
    const float* V = (const float*)d_in[2];
    const float* M = (const float*)d_in[3];
    float*       O = (float*)d_out;
    dim3 grid(S_LEN / BQ, 32);   // 16 q-tiles x (B*H)=32
    attn_fwd<<<grid, 256, 0, stream>>>(Q, K, V, M, O);
}